// Round 10
// baseline (504.285 us; speedup 1.0000x reference)
//
#include <hip/hip_runtime.h>

#define Bn 512
#define Ln 2048
#define Kn 19
#define NEGV (-1000.0f)
#define START_IDn 17
#define PAD_IDn 18
#define SEG 64               // checkpoint / staging segment (steps)
#define PBYTES 79691776u     // 512*2048*19*4

// ---------------------------------------------------------------------------
// R10 = R9 with crf_fwd's DP broadcast switched from LDS write+read to
// ds_bpermute_b32 (register crossbar pull): removes the dp array, the
// per-step ds_write, and the write->read dependency. 19 independent
// bpermutes + 19 adds + 9 max3 per step (~51 instrs vs 63, and chain =
// mydp -> bpermute -> add -> max tree instead of write -> read -> ...).
// Evidence: R5/R7 bracketed the stall as broadcast latency (~150 cy);
// readlane failed via SGPR hazards; bpermute is the SGPR-free variant.
//   crf_recbt: unchanged from R9 (passed; rec+bwd fused in LDS).
// Cross-round decomposition: ~87 µs fixed harness overhead; bwd ~13; rec ~75.
// ---------------------------------------------------------------------------

// ---------------------------------------------------------------------------
// crf_fwd — serial Viterbi DP, 2 batches per wave (half = lane>>5, c=lane&31).
// Broadcast: lane (half*32+p) holds dp[p]; everyone pulls via ds_bpermute.
// Exact reference op order: cand = dp[p] + T[c][p], best = max tree,
// new = best + emit, freeze past len (slow path only at boundary segments).
// ---------------------------------------------------------------------------
__global__ __launch_bounds__(64, 1) void crf_fwd(
    const float* __restrict__ P, const float* __restrict__ T,
    const int* __restrict__ mask, float* __restrict__ dpck,
    float* __restrict__ dpfin, int* __restrict__ lens)
{
    const int lane = threadIdx.x;
    const int half = lane >> 5;
    const int c = lane & 31;
    const int b = blockIdx.x * 2 + half;
    const int cc = (c < Kn) ? c : (Kn - 1);

    float Trow[Kn];
#pragma unroll
    for (int p = 0; p < Kn; ++p) Trow[p] = T[cc * Kn + p];

    // length = popcount of contiguous-prefix mask row
    const int* mrow = mask + (size_t)b * Ln;
    int sum = 0;
#pragma unroll
    for (int j = 0; j < Ln / 128; ++j) {
        int4 v = *(const int4*)(mrow + j * 128 + c * 4);
        sum += v.x + v.y + v.z + v.w;
    }
#pragma unroll
    for (int k = 1; k < 32; k <<= 1) sum += __shfl_xor(sum, k, 64);
    const int len = sum;
    if (c == 0) lens[b] = len;
    const int lenO = __shfl_xor(len, 32, 64);
    int maxlen = len > lenO ? len : lenO;
    int lmin = len < lenO ? len : lenO;
    lmin = __builtin_amdgcn_readfirstlane(lmin);
    int mlen = (maxlen + (SEG - 1)) & ~(SEG - 1);
    mlen = __builtin_amdgcn_readfirstlane(mlen);

    __shared__ float ebuf[2][2][1280];   // [buf][half]; 64*19=1216 used + pad

    float mydp = (c == START_IDn) ? 0.0f : NEGV;

    const unsigned bbyte = (unsigned)b * (Ln * Kn * 4u);
    const unsigned limit = PBYTES - 16;
    const char* Pc = (const char*)P;
    float4 r[10];

#define STAGE_LOAD(ci)                                                         \
    { unsigned base_ = bbyte + (unsigned)(ci) * 4864u + ((unsigned)c << 4);    \
      _Pragma("unroll")                                                        \
      for (int i_ = 0; i_ < 10; ++i_) {                                        \
          unsigned o_ = base_ + (unsigned)i_ * 512u;                           \
          if (o_ > limit) o_ = limit;                                          \
          r[i_] = *(const float4*)(Pc + o_);                                   \
      } }
#define STAGE_WRITE(nb)                                                        \
    { float* d_ = &ebuf[nb][half][(unsigned)c << 2];                           \
      _Pragma("unroll")                                                        \
      for (int i_ = 0; i_ < 10; ++i_) *(float4*)(d_ + i_ * 128) = r[i_]; }

    // bpermute byte-address base: own half's lane p lives at (lane&32)+p
    const int bpbase = (lane & 32) << 2;

#define BP(p) __int_as_float(__builtin_amdgcn_ds_bpermute(bpbase + 4 * (p), mi_))
#define STEP_FAST(EXPR_E)                                                      \
    { const float e_ = (EXPR_E);                                               \
      const int mi_ = __float_as_int(mydp);                                    \
      float c0_  = BP(0)  + Trow[0];  float c1_  = BP(1)  + Trow[1];           \
      float c2_  = BP(2)  + Trow[2];  float c3_  = BP(3)  + Trow[3];           \
      float c4_  = BP(4)  + Trow[4];  float c5_  = BP(5)  + Trow[5];           \
      float c6_  = BP(6)  + Trow[6];  float c7_  = BP(7)  + Trow[7];           \
      float c8_  = BP(8)  + Trow[8];  float c9_  = BP(9)  + Trow[9];           \
      float c10_ = BP(10) + Trow[10]; float c11_ = BP(11) + Trow[11];          \
      float c12_ = BP(12) + Trow[12]; float c13_ = BP(13) + Trow[13];          \
      float c14_ = BP(14) + Trow[14]; float c15_ = BP(15) + Trow[15];          \
      float c16_ = BP(16) + Trow[16]; float c17_ = BP(17) + Trow[17];          \
      float c18_ = BP(18) + Trow[18];                                          \
      float t0_ = fmaxf(fmaxf(c0_,  c1_),  c2_);                               \
      float t1_ = fmaxf(fmaxf(c3_,  c4_),  c5_);                               \
      float t2_ = fmaxf(fmaxf(c6_,  c7_),  c8_);                               \
      float t3_ = fmaxf(fmaxf(c9_,  c10_), c11_);                              \
      float t4_ = fmaxf(fmaxf(c12_, c13_), c14_);                              \
      float t5_ = fmaxf(fmaxf(c15_, c16_), c17_);                              \
      float u0_ = fmaxf(fmaxf(t0_, t1_), t2_);                                 \
      float u1_ = fmaxf(fmaxf(t3_, t4_), c18_);                                \
      float best_ = fmaxf(fmaxf(u0_, u1_), t5_);                               \
      mydp = best_ + e_; }
#define STEP_MASK(EXPR_E, TCOND)                                               \
    { const float e_ = (EXPR_E);                                               \
      const int mi_ = __float_as_int(mydp);                                    \
      float c0_  = BP(0)  + Trow[0];  float c1_  = BP(1)  + Trow[1];           \
      float c2_  = BP(2)  + Trow[2];  float c3_  = BP(3)  + Trow[3];           \
      float c4_  = BP(4)  + Trow[4];  float c5_  = BP(5)  + Trow[5];           \
      float c6_  = BP(6)  + Trow[6];  float c7_  = BP(7)  + Trow[7];           \
      float c8_  = BP(8)  + Trow[8];  float c9_  = BP(9)  + Trow[9];           \
      float c10_ = BP(10) + Trow[10]; float c11_ = BP(11) + Trow[11];          \
      float c12_ = BP(12) + Trow[12]; float c13_ = BP(13) + Trow[13];          \
      float c14_ = BP(14) + Trow[14]; float c15_ = BP(15) + Trow[15];          \
      float c16_ = BP(16) + Trow[16]; float c17_ = BP(17) + Trow[17];          \
      float c18_ = BP(18) + Trow[18];                                          \
      float t0_ = fmaxf(fmaxf(c0_,  c1_),  c2_);                               \
      float t1_ = fmaxf(fmaxf(c3_,  c4_),  c5_);                               \
      float t2_ = fmaxf(fmaxf(c6_,  c7_),  c8_);                               \
      float t3_ = fmaxf(fmaxf(c9_,  c10_), c11_);                              \
      float t4_ = fmaxf(fmaxf(c12_, c13_), c14_);                              \
      float t5_ = fmaxf(fmaxf(c15_, c16_), c17_);                              \
      float u0_ = fmaxf(fmaxf(t0_, t1_), t2_);                                 \
      float u1_ = fmaxf(fmaxf(t3_, t4_), c18_);                                \
      float best_ = fmaxf(fmaxf(u0_, u1_), t5_);                               \
      float nd_ = best_ + e_;                                                  \
      mydp = (TCOND) ? nd_ : mydp; }

    int buf = 0;
    STAGE_LOAD(0);
    STAGE_WRITE(0);

    for (int t0 = 0; t0 < mlen; t0 += SEG) {
        // checkpoint: DP entering step t0 (includes initial DP at t0=0)
        if (c < Kn)
            dpck[((unsigned)b * 32u + (unsigned)(t0 >> 6)) * (unsigned)Kn + (unsigned)c] = mydp;
        STAGE_LOAD((t0 >> 6) + 1);       // prefetch next segment's emissions
        const float* ebl = &ebuf[buf][half][0];

        if (t0 + SEG <= lmin) {
            // fast path: every step strictly below both lengths — no mask
            for (int tt = 0; tt < SEG; tt += 8) {
#pragma unroll
                for (int u = 0; u < 8; ++u) STEP_FAST(ebl[(tt + u) * Kn + cc]);
            }
        } else {
            for (int tt = 0; tt < SEG; tt += 8) {
#pragma unroll
                for (int u = 0; u < 8; ++u) {
                    const int t = t0 + tt + u;
                    STEP_MASK(ebl[(tt + u) * Kn + cc], t < len)
                }
            }
        }
        STAGE_WRITE(buf ^ 1);
        buf ^= 1;
    }
    if (c < Kn) dpfin[b * Kn + c] = mydp;
#undef STAGE_LOAD
#undef STAGE_WRITE
#undef STEP_FAST
#undef STEP_MASK
#undef BP
}

// ---------------------------------------------------------------------------
// Shared per-step core for recbt (LDS dp form, proven): cand[p]=dp[p]+Trow[p]
// (exact reference op order), best = depth-3 max tree.
// ---------------------------------------------------------------------------
#define DP_CORE(BASE)                                                          \
    float4 q0 = *(const float4*)((BASE) + 0);                                  \
    float4 q1 = *(const float4*)((BASE) + 4);                                  \
    float4 q2 = *(const float4*)((BASE) + 8);                                  \
    float4 q3 = *(const float4*)((BASE) + 12);                                 \
    float4 q4 = *(const float4*)((BASE) + 16); /* .w junk, unused */           \
    float cand[Kn];                                                            \
    cand[0]  = q0.x + Trow[0];  cand[1]  = q0.y + Trow[1];                     \
    cand[2]  = q0.z + Trow[2];  cand[3]  = q0.w + Trow[3];                     \
    cand[4]  = q1.x + Trow[4];  cand[5]  = q1.y + Trow[5];                     \
    cand[6]  = q1.z + Trow[6];  cand[7]  = q1.w + Trow[7];                     \
    cand[8]  = q2.x + Trow[8];  cand[9]  = q2.y + Trow[9];                     \
    cand[10] = q2.z + Trow[10]; cand[11] = q2.w + Trow[11];                    \
    cand[12] = q3.x + Trow[12]; cand[13] = q3.y + Trow[13];                    \
    cand[14] = q3.z + Trow[14]; cand[15] = q3.w + Trow[15];                    \
    cand[16] = q4.x + Trow[16]; cand[17] = q4.y + Trow[17];                    \
    cand[18] = q4.z + Trow[18];                                                \
    float m0 = fmaxf(fmaxf(cand[0],  cand[1]),  cand[2]);                      \
    float m1 = fmaxf(fmaxf(cand[3],  cand[4]),  cand[5]);                      \
    float m2 = fmaxf(fmaxf(cand[6],  cand[7]),  cand[8]);                      \
    float m3 = fmaxf(fmaxf(cand[9],  cand[10]), cand[11]);                     \
    float m4 = fmaxf(fmaxf(cand[12], cand[13]), cand[14]);                     \
    float m5 = fmaxf(fmaxf(cand[15], cand[16]), cand[17]);                     \
    float n0 = fmaxf(fmaxf(m0, m1), m2);                                       \
    float n1 = fmaxf(fmaxf(m3, m4), cand[18]);                                 \
    float best = fmaxf(fmaxf(n0, n1), m5);

// ---------------------------------------------------------------------------
// crf_recbt — FUSED recompute + backtrace, verbatim R9 (passed).
// ---------------------------------------------------------------------------
__global__ __launch_bounds__(512, 1) void crf_recbt(
    const float* __restrict__ P, const float* __restrict__ T,
    const float* __restrict__ dpck, const float* __restrict__ dpfin,
    const int* __restrict__ lens, int* __restrict__ out)
{
    const int tid = threadIdx.x;
    const int b = blockIdx.x;
    const int hw = tid >> 5;                  // 0..15 half-wave id
    const int c = tid & 31;
    const int cc = (c < Kn) ? c : (Kn - 1);
    const int len = lens[b];

    __shared__ unsigned char comp[Ln * Kn];   // 38912 B
    __shared__ float dp[16][32];              // 2 KB, 128B rows
    __shared__ int vchain[17];
    __shared__ int s_last;

    float Trow[Kn];
#pragma unroll
    for (int p = 0; p < Kn; ++p) Trow[p] = T[cc * Kn + p];

    // --- segment recompute: bit-exact replay from checkpoints -------------
#pragma unroll 1
    for (int pass = 0; pass < 2; ++pass) {
        const int seg = hw + pass * 16;       // 0..31
        const int t0 = seg * SEG;
        if (t0 < len) {
            float mydp = (c < Kn)
                ? dpck[((unsigned)b * 32u + (unsigned)seg) * (unsigned)Kn + (unsigned)c]
                : NEGV;
            dp[hw][c] = mydp;
            const float* prow = P + (size_t)b * Ln * Kn + (size_t)t0 * Kn;

            float eb[8];                      // rolling emission prefetch
#pragma unroll
            for (int u = 0; u < 8; ++u) eb[u] = prow[u * Kn + cc];

            for (int tt = 0; tt < SEG; tt += 8) {
#pragma unroll
                for (int u = 0; u < 8; ++u) {
                    const int t = t0 + tt + u;
                    const float e = eb[u];
                    const float* base_ = &dp[hw][0];
                    DP_CORE(base_)
                    float nd = best + e;
                    mydp = (t < len) ? nd : mydp;
                    dp[hw][c] = mydp;

                    // first-index argmax (jnp.argmax tie-break)
                    int arg = Kn - 1;
#pragma unroll
                    for (int p = Kn - 2; p >= 0; --p)
                        arg = (cand[p] == best) ? p : arg;
                    if (c < Kn) comp[t * Kn + c] = (unsigned char)arg;

                    int tn = tt + u + 8;      // clamped in-bounds prefetch
                    int tloc = (t0 + tn < Ln) ? tn : (Ln - 1 - t0);
                    eb[u] = prow[tloc * Kn + cc];
                }
            }
        }
    }
    __syncthreads();

    // --- phase 1: suffix-compose within each 128-step chunk, in place -----
    {
        const int wv = tid >> 6;              // 0..7
        const int lane = tid & 63;
        if (lane < 2 * Kn) {
            const int ch = wv * 2 + lane / Kn;     // 0..15
            const int c2 = lane % Kn;
            int cur = c2;
            const int tb = ch * 128 + 127;
            for (int i = 0; i < 128; ++i) {
                const int t = tb - i;
                int nv = comp[t * Kn + cur];  // cur <= 18 always: in-bounds
                cur = (t < len) ? nv : cur;   // g_t = id for t >= len
                comp[t * Kn + c2] = cur;
            }
        } else if (tid == 511) {
            // last = argmax_c( DPfinal[c] + T[PAD][c] ), first-index tie-break
            float bestv = dpfin[b * Kn + 0] + T[PAD_IDn * Kn + 0];
            int bl = 0;
            for (int ci = 1; ci < Kn; ++ci) {
                float v = dpfin[b * Kn + ci] + T[PAD_IDn * Kn + ci];
                if (v > bestv) { bestv = v; bl = ci; }
            }
            s_last = bl;
        }
    }
    __syncthreads();

    // --- phase 2: chunk-boundary chain ------------------------------------
    if (tid == 0) {
        int v = s_last;
        vchain[16] = v;
        for (int ch = 15; ch >= 0; --ch) {
            v = comp[ch * 128 * Kn + v];
            vchain[ch] = v;
        }
    }
    __syncthreads();

    // --- phase 3: emit path ------------------------------------------------
    const int last = s_last;
    int* orow = out + (size_t)b * Ln;
    for (int t = tid; t < Ln; t += 512) {
        int val;
        if (t >= len) {
            val = -1;
        } else if (t == Ln - 1) {
            val = last;                        // only reachable when len == L
        } else {
            const int tp = t + 1;
            const int vc = vchain[(tp >> 7) + 1];
            val = comp[tp * Kn + vc];
        }
        orow[t] = val;
    }
}

// ---------------------------------------------------------------------------
extern "C" void kernel_launch(void* const* d_in, const int* in_sizes, int n_in,
                              void* d_out, int out_size, void* d_ws, size_t ws_size,
                              hipStream_t stream)
{
    const float* P    = (const float*)d_in[0];
    const float* T    = (const float*)d_in[1];
    const int*   mask = (const int*)d_in[2];
    int* out = (int*)d_out;

    // workspace layout — 1.29 MB total
    float* dpck  = (float*)d_ws;                                  // 1,245,184 B
    float* dpfin = (float*)((char*)d_ws + (size_t)Bn * 32 * Kn * 4);
    int*   lens  = (int*)((char*)d_ws + (size_t)Bn * 32 * Kn * 4
                          + (size_t)Bn * Kn * 4);

    crf_fwd<<<Bn / 2, 64, 0, stream>>>(P, T, mask, dpck, dpfin, lens);
    crf_recbt<<<Bn, 512, 0, stream>>>(P, T, dpck, dpfin, lens, out);
}